// Round 1
// baseline (3522.610 us; speedup 1.0000x reference)
//
#include <hip/hip_runtime.h>
#include <math.h>

#define FEAT_H 128
#define FEAT_W 352
#define FPIX   (FEAT_H * FEAT_W)   // 45056
#define BEV    320
#define NCELL  (BEV * BEV)         // 102400
#define CH     96
#define HIDN   64

// ---- workspace layout (in floats) ----
// featS: [2][FPIX][64]  (HWC: per-pixel 64 projected channels, contiguous)
#define FEATS_ELEMS (2 * FPIX * 64)             // 5,767,168
#define OFF_HW      (FEATS_ELEMS)               // 64*64
#define OFF_BASE    (OFF_HW + 64 * 64)          // 3*64
#define OFF_BUFA    (OFF_HW + 64 * 64 + 256)    // conv intermediate [2][96][320][320]

// ---------------------------------------------------------------------------
// Precompute hW = dw2 @ sw1  (64x64) and base[h] = (db2 + he[h]) @ sw1 + sb1
// ---------------------------------------------------------------------------
__global__ void k_precompute(const float* __restrict__ dw2, const float* __restrict__ sw1,
                             const float* __restrict__ db2, const float* __restrict__ he,
                             const float* __restrict__ sb1,
                             float* __restrict__ hW, float* __restrict__ baseT) {
    const int t = threadIdx.x;
    for (int idx = t; idx < 64 * 64; idx += 256) {
        int j = idx >> 6, k = idx & 63;
        float s = 0.f;
        for (int c = 0; c < CH; c++) s = fmaf(dw2[j * CH + c], sw1[c * 64 + k], s);
        hW[idx] = s;
    }
    for (int idx = t; idx < 3 * 64; idx += 256) {
        int h = idx >> 6, k = idx & 63;
        float s = sb1[k];
        for (int c = 0; c < CH; c++) s = fmaf(db2[c] + he[h * CH + c], sw1[c * 64 + k], s);
        baseT[idx] = s;
    }
}

// ---------------------------------------------------------------------------
// featS[b][pix][64] = feat[b][:][pix] @ sw1   (channel projection, HWC out)
// 64 threads = 64 consecutive pixels. LDS-stage the 96 channels coalesced.
// ---------------------------------------------------------------------------
__global__ __launch_bounds__(64) void k_feats(const float* __restrict__ feat,
                                              const float* __restrict__ sw1,
                                              float* __restrict__ featS) {
    const int t = threadIdx.x;
    const int pb = blockIdx.x * 64;
    const int b = blockIdx.y;
    __shared__ float ld[CH * 64];
    const float* fp = feat + (size_t)b * CH * FPIX + pb;
    #pragma unroll 8
    for (int c = 0; c < CH; c++) ld[c * 64 + t] = fp[(size_t)c * FPIX + t];
    __syncthreads();

    float acc[64];
    #pragma unroll
    for (int k = 0; k < 64; k++) acc[k] = 0.f;
    for (int c = 0; c < CH; c++) {
        float x = ld[c * 64 + t];
        const float4* wr = (const float4*)(sw1 + c * 64);  // uniform -> s_load
        #pragma unroll
        for (int k4 = 0; k4 < 16; k4++) {
            float4 w = wr[k4];
            acc[4 * k4 + 0] = fmaf(x, w.x, acc[4 * k4 + 0]);
            acc[4 * k4 + 1] = fmaf(x, w.y, acc[4 * k4 + 1]);
            acc[4 * k4 + 2] = fmaf(x, w.z, acc[4 * k4 + 2]);
            acc[4 * k4 + 3] = fmaf(x, w.w, acc[4 * k4 + 3]);
        }
    }
    float4* op = (float4*)(featS + ((size_t)b * FPIX + pb + t) * 64);
    #pragma unroll
    for (int k4 = 0; k4 < 16; k4++) {
        float4 v = make_float4(acc[4 * k4 + 0], acc[4 * k4 + 1], acc[4 * k4 + 2], acc[4 * k4 + 3]);
        op[k4] = v;
    }
}

// ---------------------------------------------------------------------------
// Lift: per BEV cell, 3 heights: project, sample featS (64ch) for the score
// MLP, softmax over heights, then sample feat (96ch) weighted -> fused out.
// out layout: [b][c][320][320]  (written into d_out, used as conv1 input)
// ---------------------------------------------------------------------------
__global__ __launch_bounds__(256, 3) void k_lift(const float* __restrict__ feat,
                                                 const float* __restrict__ featS,
                                                 const float* __restrict__ l2i,
                                                 const float* __restrict__ dw1,
                                                 const float* __restrict__ db1,
                                                 const float* __restrict__ sw2,
                                                 const float* __restrict__ sb2,
                                                 const float* __restrict__ hW,
                                                 const float* __restrict__ baseT,
                                                 float* __restrict__ out) {
    const int n = blockIdx.x * 256 + threadIdx.x;
    const int b = blockIdx.y;
    const int i = n / BEV, j = n % BEV;
    const float px = ((j + 0.5f) / 320.0f) * 102.4f - 51.2f;
    const float py = ((i + 0.5f) / 320.0f) * 102.4f - 51.2f;
    const float* M = l2i + b * 16;
    const float m00 = M[0], m01 = M[1], m02 = M[2], m03 = M[3];
    const float m10 = M[4], m11 = M[5], m12 = M[6], m13 = M[7];
    const float m20 = M[8], m21 = M[9], m22 = M[10], m23 = M[11];

    const float* fSb = featS + (size_t)b * FPIX * 64;

    float logit[3];
    int   ti[3][4];
    float tw[3][4];

    #pragma unroll
    for (int h = 0; h < 3; h++) {
        logit[h] = -INFINITY;
        const float z = (float)h;
        float p0 = m03 + m00 * px + m01 * py + m02 * z;
        float p1 = m13 + m10 * px + m11 * py + m12 * z;
        float dep = m23 + m20 * px + m21 * py + m22 * z;
        float dv = fmaxf(dep, 1e-5f);
        float u = p0 / dv, v = p1 / dv;
        float gx = (u / 351.0f) * 2.0f - 1.0f;
        float gy = (v / 127.0f) * 2.0f - 1.0f;
        bool valid = (dep > 1e-3f) && (fabsf(gx) <= 1.0f) && (fabsf(gy) <= 1.0f);
        if (!valid) continue;

        float xs = (gx + 1.0f) * 0.5f * 351.0f;
        float ys = (gy + 1.0f) * 0.5f * 127.0f;
        float xf = floorf(xs), yf = floorf(ys);
        int x0 = (int)xf, y0 = (int)yf;
        float wx = xs - xf, wy = ys - yf;
        int x1 = (x0 < FEAT_W - 1) ? x0 + 1 : x0;   // clamped dup has weight exactly 0
        int y1 = (y0 < FEAT_H - 1) ? y0 + 1 : y0;
        ti[h][0] = y0 * FEAT_W + x0;
        ti[h][1] = y0 * FEAT_W + x1;
        ti[h][2] = y1 * FEAT_W + x0;
        ti[h][3] = y1 * FEAT_W + x1;
        tw[h][0] = (1.f - wx) * (1.f - wy);
        tw[h][1] = wx * (1.f - wy);
        tw[h][2] = (1.f - wx) * wy;
        tw[h][3] = wx * wy;

        // hid = base[h] + bilinear(featS) + relu(d*dw1+db1) @ hW
        float hid[64];
        {
            const float* bs = baseT + h * 64;   // uniform -> s_load
            #pragma unroll
            for (int k = 0; k < 64; k++) hid[k] = bs[k];
        }
        #pragma unroll
        for (int t = 0; t < 4; t++) {
            const float wt = tw[h][t];
            const float4* p = (const float4*)(fSb + (size_t)ti[h][t] * 64);
            #pragma unroll
            for (int k4 = 0; k4 < 16; k4++) {
                float4 vv = p[k4];
                hid[4 * k4 + 0] = fmaf(wt, vv.x, hid[4 * k4 + 0]);
                hid[4 * k4 + 1] = fmaf(wt, vv.y, hid[4 * k4 + 1]);
                hid[4 * k4 + 2] = fmaf(wt, vv.z, hid[4 * k4 + 2]);
                hid[4 * k4 + 3] = fmaf(wt, vv.w, hid[4 * k4 + 3]);
            }
        }
        const float dl = log1pf(fmaxf(dep, 1e-3f));
        #pragma unroll 4
        for (int jj = 0; jj < 64; jj++) {
            float hd = fmaxf(fmaf(dl, dw1[jj], db1[jj]), 0.f);  // dw1/db1 uniform
            const float4* hr = (const float4*)(hW + jj * 64);   // uniform -> s_load
            #pragma unroll
            for (int k4 = 0; k4 < 16; k4++) {
                float4 wv = hr[k4];
                hid[4 * k4 + 0] = fmaf(hd, wv.x, hid[4 * k4 + 0]);
                hid[4 * k4 + 1] = fmaf(hd, wv.y, hid[4 * k4 + 1]);
                hid[4 * k4 + 2] = fmaf(hd, wv.z, hid[4 * k4 + 2]);
                hid[4 * k4 + 3] = fmaf(hd, wv.w, hid[4 * k4 + 3]);
            }
        }
        float lg = sb2[0];
        const float4* s2 = (const float4*)sw2;
        #pragma unroll
        for (int k4 = 0; k4 < 16; k4++) {
            float4 wv = s2[k4];
            lg = fmaf(fmaxf(hid[4 * k4 + 0], 0.f), wv.x, lg);
            lg = fmaf(fmaxf(hid[4 * k4 + 1], 0.f), wv.y, lg);
            lg = fmaf(fmaxf(hid[4 * k4 + 2], 0.f), wv.z, lg);
            lg = fmaf(fmaxf(hid[4 * k4 + 3], 0.f), wv.w, lg);
        }
        logit[h] = lg;
    }

    // softmax over heights (invalid = -inf; all-invalid -> weights 0)
    float mx = fmaxf(logit[0], fmaxf(logit[1], logit[2]));
    float wh[3] = {0.f, 0.f, 0.f};
    if (mx > -INFINITY) {
        float s = 0.f;
        #pragma unroll
        for (int h = 0; h < 3; h++) {
            if (logit[h] > -INFINITY) { wh[h] = expf(logit[h] - mx); s += wh[h]; }
        }
        float inv = 1.0f / s;
        wh[0] *= inv; wh[1] *= inv; wh[2] *= inv;
    }

    // fused = sum_h wh[h] * bilinear_96ch(feat)
    float acc[CH];
    #pragma unroll
    for (int c = 0; c < CH; c++) acc[c] = 0.f;
    const float* fB = feat + (size_t)b * CH * FPIX;
    #pragma unroll
    for (int h = 0; h < 3; h++) {
        if (wh[h] > 0.f) {
            const float w0 = tw[h][0], w1 = tw[h][1], w2 = tw[h][2], w3 = tw[h][3];
            const int i0 = ti[h][0], i1 = ti[h][1], i2 = ti[h][2], i3 = ti[h][3];
            const float whh = wh[h];
            for (int c = 0; c < CH; c++) {
                const float* p = fB + (size_t)c * FPIX;
                float sv = w0 * p[i0] + w1 * p[i1] + w2 * p[i2] + w3 * p[i3];
                acc[c] = fmaf(whh, sv, acc[c]);
            }
        }
    }
    float* op = out + (size_t)b * CH * NCELL + n;
    #pragma unroll
    for (int c = 0; c < CH; c++) op[(size_t)c * NCELL] = acc[c];
}

// ---------------------------------------------------------------------------
// 3x3 conv + BN + ReLU, fp32 direct. 16x16 out tile / 256 threads.
// Weights fetched with wave-uniform indices (scalar-load path); input tile
// staged in LDS per 16-ic chunk.
// ---------------------------------------------------------------------------
__global__ __launch_bounds__(256, 4) void k_conv(const float* __restrict__ in,
                                                 float* __restrict__ out,
                                                 const float* __restrict__ w,
                                                 const float* __restrict__ bng,
                                                 const float* __restrict__ bnb,
                                                 const float* __restrict__ bnm,
                                                 const float* __restrict__ bnv) {
    __shared__ float sin_[16 * 324];  // 16 ic x 18 x 18
    const int tx = threadIdx.x & 15, ty = threadIdx.x >> 4;
    const int x0 = blockIdx.x * 16, y0 = blockIdx.y * 16;
    const int b = blockIdx.z;
    const float* inb = in + (size_t)b * CH * NCELL;
    float* outb = out + (size_t)b * CH * NCELL;

    for (int ocb = 0; ocb < CH; ocb += 24) {
        float acc[24];
        #pragma unroll
        for (int o = 0; o < 24; o++) acc[o] = 0.f;

        for (int icb = 0; icb < CH; icb += 16) {
            __syncthreads();
            for (int idx = threadIdx.x; idx < 16 * 324; idx += 256) {
                int ic = idx / 324;
                int rem = idx - ic * 324;
                int r = rem / 18, cc = rem - r * 18;
                int gy = y0 + r - 1, gx = x0 + cc - 1;
                float v = 0.f;
                if ((unsigned)gy < 320u && (unsigned)gx < 320u)
                    v = inb[(size_t)(icb + ic) * NCELL + gy * 320 + gx];
                sin_[idx] = v;
            }
            __syncthreads();

            for (int ic = 0; ic < 16; ic++) {
                const float* sp = sin_ + ic * 324 + ty * 18 + tx;
                float v0 = sp[0],  v1 = sp[1],  v2 = sp[2];
                float v3 = sp[18], v4 = sp[19], v5 = sp[20];
                float v6 = sp[36], v7 = sp[37], v8 = sp[38];
                const float* wr = w + ((size_t)ocb * CH + (icb + ic)) * 9;
                #pragma unroll
                for (int o = 0; o < 24; o++) {
                    const float* wo = wr + (size_t)o * CH * 9;  // uniform -> s_load
                    float s = fmaf(wo[0], v0, fmaf(wo[1], v1, fmaf(wo[2], v2,
                              fmaf(wo[3], v3, fmaf(wo[4], v4, fmaf(wo[5], v5,
                              fmaf(wo[6], v6, fmaf(wo[7], v7, wo[8] * v8))))))));
                    acc[o] += s;
                }
            }
        }

        const int ox = x0 + tx, oy = y0 + ty;
        #pragma unroll
        for (int o = 0; o < 24; o++) {
            int oc = ocb + o;
            float sc = bng[oc] * rsqrtf(bnv[oc] + 1e-3f);
            float sh = fmaf(-bnm[oc], sc, bnb[oc]);
            float r = fmaxf(fmaf(acc[o], sc, sh), 0.f);
            outb[(size_t)oc * NCELL + oy * 320 + ox] = r;
        }
    }
}

// ---------------------------------------------------------------------------
extern "C" void kernel_launch(void* const* d_in, const int* in_sizes, int n_in,
                              void* d_out, int out_size, void* d_ws, size_t ws_size,
                              hipStream_t stream) {
    const float* feat = (const float*)d_in[0];
    const float* l2i  = (const float*)d_in[1];
    const float* he   = (const float*)d_in[2];
    const float* dw1  = (const float*)d_in[3];
    const float* db1  = (const float*)d_in[4];
    const float* dw2  = (const float*)d_in[5];
    const float* db2  = (const float*)d_in[6];
    const float* sw1  = (const float*)d_in[7];
    const float* sb1  = (const float*)d_in[8];
    const float* sw2  = (const float*)d_in[9];
    const float* sb2  = (const float*)d_in[10];
    const float* c1w  = (const float*)d_in[11];
    const float* bn1g = (const float*)d_in[12];
    const float* bn1b = (const float*)d_in[13];
    const float* bn1m = (const float*)d_in[14];
    const float* bn1v = (const float*)d_in[15];
    const float* c2w  = (const float*)d_in[16];
    const float* bn2g = (const float*)d_in[17];
    const float* bn2b = (const float*)d_in[18];
    const float* bn2m = (const float*)d_in[19];
    const float* bn2v = (const float*)d_in[20];

    float* ws    = (float*)d_ws;
    float* featS = ws;
    float* hW    = ws + OFF_HW;
    float* baseT = ws + OFF_BASE;
    float* bufA  = ws + OFF_BUFA;
    float* fused = (float*)d_out;   // d_out doubles as the fused BEV buffer

    hipLaunchKernelGGL(k_precompute, dim3(1), dim3(256), 0, stream,
                       dw2, sw1, db2, he, sb1, hW, baseT);
    hipLaunchKernelGGL(k_feats, dim3(FPIX / 64, 2), dim3(64), 0, stream,
                       feat, sw1, featS);
    hipLaunchKernelGGL(k_lift, dim3(NCELL / 256, 2), dim3(256), 0, stream,
                       feat, featS, l2i, dw1, db1, sw2, sb2, hW, baseT, fused);
    hipLaunchKernelGGL(k_conv, dim3(20, 20, 2), dim3(256), 0, stream,
                       fused, bufA, c1w, bn1g, bn1b, bn1m, bn1v);
    hipLaunchKernelGGL(k_conv, dim3(20, 20, 2), dim3(256), 0, stream,
                       bufA, (float*)d_out, c2w, bn2g, bn2b, bn2m, bn2v);
}

// Round 2
// 581.505 us; speedup vs baseline: 6.0577x; 6.0577x over previous
//
#include <hip/hip_runtime.h>
#include <math.h>

typedef _Float16 f16x8 __attribute__((ext_vector_type(8)));
typedef float    f32x4 __attribute__((ext_vector_type(4)));

#define FEAT_H 128
#define FEAT_W 352
#define FPIX   (FEAT_H * FEAT_W)   // 45056
#define BEV    320
#define NCELL  (BEV * BEV)         // 102400
#define CH     96
#define PD     322                 // padded spatial dim
#define PPIX   (PD * PD)           // 103684

// ---- workspace layout (float offsets) ----
// bufPadB (f16 [2][322][322][96]) at 0; featS (fp32 [2][FPIX][64]) ALIASES it
//   (featS = 5,767,168 floats < bufPadB = 9,953,664 floats; featS is dead
//    before conv1 writes bufPadB).
#define N_PADF    (2 * PPIX * CH / 2)            // 9,953,664 floats (f16 buffer)
#define OFF_BUFB  0
#define OFF_WT    (N_PADF)                       // f16 2*9*96*96 = 82,944 floats
#define OFF_HW    (OFF_WT + 82944)               // 64*64 fp32
#define OFF_BASE  (OFF_HW + 4096)                // 3*64 fp32 (pad 256)
#define OFF_BUFA  (OFF_BASE + 256)               // f16 padded conv1 input

// ---------------------------------------------------------------------------
// hW = dw2 @ sw1 (64x64); base[h] = (db2 + he[h]) @ sw1 + sb1
// ---------------------------------------------------------------------------
__global__ void k_precompute(const float* __restrict__ dw2, const float* __restrict__ sw1,
                             const float* __restrict__ db2, const float* __restrict__ he,
                             const float* __restrict__ sb1,
                             float* __restrict__ hW, float* __restrict__ baseT) {
    const int t = threadIdx.x;
    for (int idx = t; idx < 64 * 64; idx += 256) {
        int j = idx >> 6, k = idx & 63;
        float s = 0.f;
        for (int c = 0; c < CH; c++) s = fmaf(dw2[j * CH + c], sw1[c * 64 + k], s);
        hW[idx] = s;
    }
    for (int idx = t; idx < 3 * 64; idx += 256) {
        int h = idx >> 6, k = idx & 63;
        float s = sb1[k];
        for (int c = 0; c < CH; c++) s = fmaf(db2[c] + he[h * CH + c], sw1[c * 64 + k], s);
        baseT[idx] = s;
    }
}

// ---------------------------------------------------------------------------
// Weight prep: wt[cv][tap][oc][ic] (f16)  from  w[oc][ic][3][3] (fp32)
// ---------------------------------------------------------------------------
__global__ void k_wprep(const float* __restrict__ w1, const float* __restrict__ w2,
                        _Float16* __restrict__ wt) {
    int idx = blockIdx.x * 256 + threadIdx.x;       // 2*9*96*96 = 165888
    if (idx >= 165888) return;
    int cv = idx / 82944; int r = idx - cv * 82944;
    int tap = r / 9216;   int rr = r - tap * 9216;
    int oc = rr / 96;     int ic = rr - oc * 96;
    const float* src = cv ? w2 : w1;
    wt[idx] = (_Float16)src[(oc * 96 + ic) * 9 + tap];
}

// ---------------------------------------------------------------------------
// Zero the 1-pixel border of a padded f16 HWC buffer [2][322][322][96]
// ---------------------------------------------------------------------------
__global__ void k_border(_Float16* __restrict__ buf) {
    int idx = blockIdx.x * 256 + threadIdx.x;       // 2*1284 = 2568 border pixels
    if (idx >= 2568) return;
    int img = idx / 1284; int p = idx - img * 1284;
    int row, col;
    if (p < 322)      { row = 0;           col = p; }
    else if (p < 644) { row = 321;         col = p - 322; }
    else if (p < 964) { row = p - 644 + 1; col = 0; }
    else              { row = p - 964 + 1; col = 321; }
    _Float16* q = buf + ((size_t)(img * PD + row) * PD + col) * CH;
    f16x8 z = {};
    #pragma unroll
    for (int c8 = 0; c8 < 12; ++c8) *(f16x8*)(q + c8 * 8) = z;
}

// ---------------------------------------------------------------------------
// featS[b][pix][64] = feat[b][:][pix] @ sw1
// ---------------------------------------------------------------------------
__global__ __launch_bounds__(64) void k_feats(const float* __restrict__ feat,
                                              const float* __restrict__ sw1,
                                              float* __restrict__ featS) {
    const int t = threadIdx.x;
    const int pb = blockIdx.x * 64;
    const int b = blockIdx.y;
    __shared__ float ld[CH * 64];
    const float* fp = feat + (size_t)b * CH * FPIX + pb;
    #pragma unroll 8
    for (int c = 0; c < CH; c++) ld[c * 64 + t] = fp[(size_t)c * FPIX + t];
    __syncthreads();

    float acc[64];
    #pragma unroll
    for (int k = 0; k < 64; k++) acc[k] = 0.f;
    for (int c = 0; c < CH; c++) {
        float x = ld[c * 64 + t];
        const float4* wr = (const float4*)(sw1 + c * 64);
        #pragma unroll
        for (int k4 = 0; k4 < 16; k4++) {
            float4 w = wr[k4];
            acc[4 * k4 + 0] = fmaf(x, w.x, acc[4 * k4 + 0]);
            acc[4 * k4 + 1] = fmaf(x, w.y, acc[4 * k4 + 1]);
            acc[4 * k4 + 2] = fmaf(x, w.z, acc[4 * k4 + 2]);
            acc[4 * k4 + 3] = fmaf(x, w.w, acc[4 * k4 + 3]);
        }
    }
    float4* op = (float4*)(featS + ((size_t)b * FPIX + pb + t) * 64);
    #pragma unroll
    for (int k4 = 0; k4 < 16; k4++)
        op[k4] = make_float4(acc[4 * k4 + 0], acc[4 * k4 + 1], acc[4 * k4 + 2], acc[4 * k4 + 3]);
}

// ---------------------------------------------------------------------------
// Lift -> padded HWC f16 buffer (conv1 input), interior pixels only.
// ---------------------------------------------------------------------------
__global__ __launch_bounds__(256, 3) void k_lift(const float* __restrict__ feat,
                                                 const float* __restrict__ featS,
                                                 const float* __restrict__ l2i,
                                                 const float* __restrict__ dw1,
                                                 const float* __restrict__ db1,
                                                 const float* __restrict__ sw2,
                                                 const float* __restrict__ sb2,
                                                 const float* __restrict__ hW,
                                                 const float* __restrict__ baseT,
                                                 _Float16* __restrict__ out) {
    const int n = blockIdx.x * 256 + threadIdx.x;
    const int b = blockIdx.y;
    const int i = n / BEV, j = n % BEV;
    const float px = ((j + 0.5f) / 320.0f) * 102.4f - 51.2f;
    const float py = ((i + 0.5f) / 320.0f) * 102.4f - 51.2f;
    const float* M = l2i + b * 16;
    const float m00 = M[0], m01 = M[1], m02 = M[2], m03 = M[3];
    const float m10 = M[4], m11 = M[5], m12 = M[6], m13 = M[7];
    const float m20 = M[8], m21 = M[9], m22 = M[10], m23 = M[11];

    const float* fSb = featS + (size_t)b * FPIX * 64;

    float logit[3];
    int   ti[3][4];
    float tw[3][4];

    #pragma unroll
    for (int h = 0; h < 3; h++) {
        logit[h] = -INFINITY;
        const float z = (float)h;
        float p0 = m03 + m00 * px + m01 * py + m02 * z;
        float p1 = m13 + m10 * px + m11 * py + m12 * z;
        float dep = m23 + m20 * px + m21 * py + m22 * z;
        float dv = fmaxf(dep, 1e-5f);
        float u = p0 / dv, v = p1 / dv;
        float gx = (u / 351.0f) * 2.0f - 1.0f;
        float gy = (v / 127.0f) * 2.0f - 1.0f;
        bool valid = (dep > 1e-3f) && (fabsf(gx) <= 1.0f) && (fabsf(gy) <= 1.0f);
        if (!valid) continue;

        float xs = (gx + 1.0f) * 0.5f * 351.0f;
        float ys = (gy + 1.0f) * 0.5f * 127.0f;
        float xf = floorf(xs), yf = floorf(ys);
        int x0 = (int)xf, y0 = (int)yf;
        float wx = xs - xf, wy = ys - yf;
        int x1 = (x0 < FEAT_W - 1) ? x0 + 1 : x0;
        int y1 = (y0 < FEAT_H - 1) ? y0 + 1 : y0;
        ti[h][0] = y0 * FEAT_W + x0;
        ti[h][1] = y0 * FEAT_W + x1;
        ti[h][2] = y1 * FEAT_W + x0;
        ti[h][3] = y1 * FEAT_W + x1;
        tw[h][0] = (1.f - wx) * (1.f - wy);
        tw[h][1] = wx * (1.f - wy);
        tw[h][2] = (1.f - wx) * wy;
        tw[h][3] = wx * wy;

        float hid[64];
        {
            const float* bs = baseT + h * 64;
            #pragma unroll
            for (int k = 0; k < 64; k++) hid[k] = bs[k];
        }
        #pragma unroll
        for (int t = 0; t < 4; t++) {
            const float wt = tw[h][t];
            const float4* p = (const float4*)(fSb + (size_t)ti[h][t] * 64);
            #pragma unroll
            for (int k4 = 0; k4 < 16; k4++) {
                float4 vv = p[k4];
                hid[4 * k4 + 0] = fmaf(wt, vv.x, hid[4 * k4 + 0]);
                hid[4 * k4 + 1] = fmaf(wt, vv.y, hid[4 * k4 + 1]);
                hid[4 * k4 + 2] = fmaf(wt, vv.z, hid[4 * k4 + 2]);
                hid[4 * k4 + 3] = fmaf(wt, vv.w, hid[4 * k4 + 3]);
            }
        }
        const float dl = log1pf(fmaxf(dep, 1e-3f));
        #pragma unroll 4
        for (int jj = 0; jj < 64; jj++) {
            float hd = fmaxf(fmaf(dl, dw1[jj], db1[jj]), 0.f);
            const float4* hr = (const float4*)(hW + jj * 64);
            #pragma unroll
            for (int k4 = 0; k4 < 16; k4++) {
                float4 wv = hr[k4];
                hid[4 * k4 + 0] = fmaf(hd, wv.x, hid[4 * k4 + 0]);
                hid[4 * k4 + 1] = fmaf(hd, wv.y, hid[4 * k4 + 1]);
                hid[4 * k4 + 2] = fmaf(hd, wv.z, hid[4 * k4 + 2]);
                hid[4 * k4 + 3] = fmaf(hd, wv.w, hid[4 * k4 + 3]);
            }
        }
        float lg = sb2[0];
        const float4* s2 = (const float4*)sw2;
        #pragma unroll
        for (int k4 = 0; k4 < 16; k4++) {
            float4 wv = s2[k4];
            lg = fmaf(fmaxf(hid[4 * k4 + 0], 0.f), wv.x, lg);
            lg = fmaf(fmaxf(hid[4 * k4 + 1], 0.f), wv.y, lg);
            lg = fmaf(fmaxf(hid[4 * k4 + 2], 0.f), wv.z, lg);
            lg = fmaf(fmaxf(hid[4 * k4 + 3], 0.f), wv.w, lg);
        }
        logit[h] = lg;
    }

    float mx = fmaxf(logit[0], fmaxf(logit[1], logit[2]));
    float wh[3] = {0.f, 0.f, 0.f};
    if (mx > -INFINITY) {
        float s = 0.f;
        #pragma unroll
        for (int h = 0; h < 3; h++) {
            if (logit[h] > -INFINITY) { wh[h] = expf(logit[h] - mx); s += wh[h]; }
        }
        float inv = 1.0f / s;
        wh[0] *= inv; wh[1] *= inv; wh[2] *= inv;
    }

    float acc[CH];
    #pragma unroll
    for (int c = 0; c < CH; c++) acc[c] = 0.f;
    const float* fB = feat + (size_t)b * CH * FPIX;
    #pragma unroll
    for (int h = 0; h < 3; h++) {
        if (wh[h] > 0.f) {
            const float w0 = tw[h][0], w1 = tw[h][1], w2 = tw[h][2], w3 = tw[h][3];
            const int i0 = ti[h][0], i1 = ti[h][1], i2 = ti[h][2], i3 = ti[h][3];
            const float whh = wh[h];
            for (int c = 0; c < CH; c++) {
                const float* p = fB + (size_t)c * FPIX;
                float sv = w0 * p[i0] + w1 * p[i1] + w2 * p[i2] + w3 * p[i3];
                acc[c] = fmaf(whh, sv, acc[c]);
            }
        }
    }
    // store padded HWC f16
    _Float16* op = out + ((size_t)(b * PD + i + 1) * PD + (j + 1)) * CH;
    #pragma unroll
    for (int c8 = 0; c8 < 12; ++c8) {
        f16x8 v;
        #pragma unroll
        for (int k = 0; k < 8; ++k) v[k] = (_Float16)acc[c8 * 8 + k];
        *(f16x8*)(op + c8 * 8) = v;
    }
}

// ---------------------------------------------------------------------------
// Conv 3x3 + BN + ReLU via f16 MFMA implicit GEMM (9 shifted GEMMs).
// Block: 4 rows x 32 cols x 96 oc. 4 waves; wave = 1 row, 2 Mtiles x 6 Ntiles.
// Input: padded HWC f16. MODE 0: out padded HWC f16. MODE 1: out CHW fp32.
// ---------------------------------------------------------------------------
template<int MODE>
__global__ __launch_bounds__(256, 3) void k_conv_mfma(
        const _Float16* __restrict__ in, const _Float16* __restrict__ wt,
        const float* __restrict__ bng, const float* __restrict__ bnb,
        const float* __restrict__ bnm, const float* __restrict__ bnv,
        void* __restrict__ outv) {
    __shared__ __align__(16) unsigned char smem[49664];  // max(42432 stage, 49664 transpose)
    _Float16* sin = (_Float16*)smem;
    const int tid = threadIdx.x;
    const int x0 = blockIdx.x * 32, y0 = blockIdx.y * 4, b = blockIdx.z;
    const _Float16* inb = in + (size_t)b * PPIX * CH;

    // stage 6x34x96 input halo tile, pixel stride padded to 104 f16 (16B-aligned)
    for (int idx = tid; idx < 204 * 12; idx += 256) {
        int pix = idx / 12, ch = (idx - pix * 12) * 8;
        int rr = pix / 34, cc = pix - rr * 34;
        f16x8 v = *(const f16x8*)(inb + ((size_t)(y0 + rr) * PD + (x0 + cc)) * CH + ch);
        *(f16x8*)(sin + pix * 104 + ch) = v;
    }
    __syncthreads();

    const int w = tid >> 6, lane = tid & 63, q = lane >> 4, n = lane & 15;

    f32x4 acc[2][6];
    #pragma unroll
    for (int mt = 0; mt < 2; mt++)
        #pragma unroll
        for (int nt = 0; nt < 6; nt++) acc[mt][nt] = (f32x4){0.f, 0.f, 0.f, 0.f};

    for (int r = 0; r < 3; ++r) {
        for (int s = 0; s < 3; ++s) {
            const _Float16* wtap = wt + (size_t)(r * 3 + s) * CH * CH;
            const _Float16* arow = sin + ((w + r) * 34 + s + n) * 104 + q * 8;
            #pragma unroll
            for (int kc = 0; kc < 3; ++kc) {
                f16x8 a0 = *(const f16x8*)(arow + kc * 32);
                f16x8 a1 = *(const f16x8*)(arow + 16 * 104 + kc * 32);
                #pragma unroll
                for (int nt = 0; nt < 6; ++nt) {
                    f16x8 bf = *(const f16x8*)(wtap + (nt * 16 + n) * CH + kc * 32 + q * 8);
                    acc[0][nt] = __builtin_amdgcn_mfma_f32_16x16x32_f16(a0, bf, acc[0][nt], 0, 0, 0);
                    acc[1][nt] = __builtin_amdgcn_mfma_f32_16x16x32_f16(a1, bf, acc[1][nt], 0, 0, 0);
                }
            }
        }
    }

    if (MODE == 0) {
        // BN+ReLU -> padded HWC f16
        _Float16* outb = (_Float16*)outv + (size_t)b * PPIX * CH;
        const int orow = y0 + w + 1;
        #pragma unroll
        for (int nt = 0; nt < 6; ++nt) {
            int oc = nt * 16 + n;
            float sc = bng[oc] * rsqrtf(bnv[oc] + 1e-3f);
            float sh = fmaf(-bnm[oc], sc, bnb[oc]);
            #pragma unroll
            for (int mt = 0; mt < 2; ++mt)
                #pragma unroll
                for (int rg = 0; rg < 4; ++rg) {
                    int ocol = x0 + mt * 16 + q * 4 + rg + 1;
                    float val = fmaxf(fmaf(acc[mt][nt][rg], sc, sh), 0.f);
                    outb[((size_t)orow * PD + ocol) * CH + oc] = (_Float16)val;
                }
        }
    } else {
        // BN+ReLU -> LDS transpose -> coalesced CHW fp32
        __syncthreads();
        float* st = (float*)smem;
        #pragma unroll
        for (int nt = 0; nt < 6; ++nt) {
            int oc = nt * 16 + n;
            float sc = bng[oc] * rsqrtf(bnv[oc] + 1e-3f);
            float sh = fmaf(-bnm[oc], sc, bnb[oc]);
            #pragma unroll
            for (int mt = 0; mt < 2; ++mt)
                #pragma unroll
                for (int rg = 0; rg < 4; ++rg) {
                    int pix = w * 32 + mt * 16 + q * 4 + rg;
                    st[pix * 97 + oc] = fmaxf(fmaf(acc[mt][nt][rg], sc, sh), 0.f);
                }
        }
        __syncthreads();
        float* outb = (float*)outv + (size_t)b * CH * NCELL;
        #pragma unroll 4
        for (int it = 0; it < 48; ++it) {
            int oc = it * 2 + (tid >> 7);
            int pix = tid & 127;
            int row = y0 + (pix >> 5), col = x0 + (pix & 31);
            outb[(size_t)oc * NCELL + row * BEV + col] = st[pix * 97 + oc];
        }
    }
}

// ---------------------------------------------------------------------------
extern "C" void kernel_launch(void* const* d_in, const int* in_sizes, int n_in,
                              void* d_out, int out_size, void* d_ws, size_t ws_size,
                              hipStream_t stream) {
    const float* feat = (const float*)d_in[0];
    const float* l2i  = (const float*)d_in[1];
    const float* he   = (const float*)d_in[2];
    const float* dw1  = (const float*)d_in[3];
    const float* db1  = (const float*)d_in[4];
    const float* dw2  = (const float*)d_in[5];
    const float* db2  = (const float*)d_in[6];
    const float* sw1  = (const float*)d_in[7];
    const float* sb1  = (const float*)d_in[8];
    const float* sw2  = (const float*)d_in[9];
    const float* sb2  = (const float*)d_in[10];
    const float* c1w  = (const float*)d_in[11];
    const float* bn1g = (const float*)d_in[12];
    const float* bn1b = (const float*)d_in[13];
    const float* bn1m = (const float*)d_in[14];
    const float* bn1v = (const float*)d_in[15];
    const float* c2w  = (const float*)d_in[16];
    const float* bn2g = (const float*)d_in[17];
    const float* bn2b = (const float*)d_in[18];
    const float* bn2m = (const float*)d_in[19];
    const float* bn2v = (const float*)d_in[20];

    float* ws = (float*)d_ws;
    float*     featS = ws + OFF_BUFB;               // aliases bufB (dead before conv1)
    _Float16*  bufB  = (_Float16*)(ws + OFF_BUFB);
    _Float16*  wtp   = (_Float16*)(ws + OFF_WT);
    float*     hW    = ws + OFF_HW;
    float*     baseT = ws + OFF_BASE;
    _Float16*  bufA  = (_Float16*)(ws + OFF_BUFA);
    _Float16*  wt1   = wtp;
    _Float16*  wt2   = wtp + 82944;

    hipLaunchKernelGGL(k_precompute, dim3(1), dim3(256), 0, stream,
                       dw2, sw1, db2, he, sb1, hW, baseT);
    hipLaunchKernelGGL(k_wprep, dim3(648), dim3(256), 0, stream, c1w, c2w, wtp);
    hipLaunchKernelGGL(k_feats, dim3(FPIX / 64, 2), dim3(64), 0, stream,
                       feat, sw1, featS);
    hipLaunchKernelGGL(k_border, dim3(11), dim3(256), 0, stream, bufA);
    hipLaunchKernelGGL(k_lift, dim3(NCELL / 256, 2), dim3(256), 0, stream,
                       feat, featS, l2i, dw1, db1, sw2, sb2, hW, baseT, bufA);
    // bufB borders: only after k_lift (featS aliases bufB)
    hipLaunchKernelGGL(k_border, dim3(11), dim3(256), 0, stream, bufB);
    hipLaunchKernelGGL((k_conv_mfma<0>), dim3(10, 80, 2), dim3(256), 0, stream,
                       bufA, wt1, bn1g, bn1b, bn1m, bn1v, (void*)bufB);
    hipLaunchKernelGGL((k_conv_mfma<1>), dim3(10, 80, 2), dim3(256), 0, stream,
                       bufB, wt2, bn2g, bn2b, bn2m, bn2v, d_out);
}